// Round 14
// baseline (583.763 us; speedup 1.0000x reference)
//
#include <hip/hip_runtime.h>
#include <math.h>

#define HH 19
#define NG 57
#define SL 64        // padded slots per xg row (128B line)
#define NB 1024
#define TT 2048

typedef float v2f __attribute__((ext_vector_type(2)));
typedef unsigned u2 __attribute__((ext_vector_type(2)));
typedef unsigned u32x4 __attribute__((ext_vector_type(4)));
typedef unsigned u32x2 __attribute__((ext_vector_type(2)));
typedef _Float16 v2h __attribute__((ext_vector_type(2)));

__device__ __forceinline__ float rlf(float v, int l) {
  return __uint_as_float(__builtin_amdgcn_readlane(__float_as_uint(v), l));
}
__device__ __forceinline__ float frcp(float v) { return __builtin_amdgcn_rcpf(v); }
__device__ __forceinline__ float fexp2(float v) {
#if __has_builtin(__builtin_amdgcn_exp2f)
  return __builtin_amdgcn_exp2f(v);
#else
  return exp2f(v);
#endif
}
__device__ __forceinline__ unsigned short f2h(float f) {
  return __builtin_bit_cast(unsigned short, (_Float16)f);
}
__device__ __forceinline__ float h2f(unsigned short u) {
  return (float)__builtin_bit_cast(_Float16, u);
}
__device__ __forceinline__ v2f mk2(float a, float b) { v2f r; r.x = a; r.y = b; return r; }
__device__ __forceinline__ v2f vfma(v2f a, v2f b, v2f c) {
#if __has_builtin(__builtin_elementwise_fma)
  return __builtin_elementwise_fma(a, b, c);
#else
  v2f r; r.x = fmaf(a.x, b.x, c.x); r.y = fmaf(a.y, b.y, c.y); return r;
#endif
}

// v_dot2_f32_f16: w.x*d.lo + w.y*d.hi + acc (f32 accumulate, full rate)
#if __has_builtin(__builtin_amdgcn_fdot2)
__device__ __forceinline__ float dot2h(v2h w, unsigned d, float acc) {
  return __builtin_amdgcn_fdot2(w, __builtin_bit_cast(v2h, d), acc, false);
}
#else
__device__ __forceinline__ float dot2h(v2h w, unsigned d, float acc) {
  const float fl = h2f((unsigned short)(d & 0xffffu));
  const float fh = h2f((unsigned short)(d >> 16));
  return fmaf((float)w.x, fl, fmaf((float)w.y, fh, acc));
}
#endif

#if __has_builtin(__builtin_amdgcn_permlane32_swap)
#define HAVE_PLS 1
__device__ __forceinline__ u2 pls(float x) {
  unsigned u = __float_as_uint(x);
  return __builtin_amdgcn_permlane32_swap(u, u, false, false);
}
#else
#define HAVE_PLS 0
#endif

// ---------------- K1: x-projection, thread = pair (proven ~110us) ---------
// xg[pair][g] slots: g<38 -> -L2E*(x·Wih_g+bih_g+bhh_g); g>=38 -> 2L2E*(x·Wih_g+bih_g)
__global__ __launch_bounds__(256) void xg_proj4(
    const float* __restrict__ x, const float* __restrict__ Wih,
    const float* __restrict__ bih, const float* __restrict__ bhh,
    unsigned short* __restrict__ xg)
{
  __shared__ __align__(16) float ls[256 * 33];
  const int tid = threadIdx.x;
  const size_t pair0 = (size_t)blockIdx.x * 256;
  const float L2E = 1.4426950408889634f;

  {
    const float* __restrict__ src = x + pair0 * HH;
#pragma unroll
    for (int j = 0; j < HH; ++j) ls[j * 256 + tid] = src[j * 256 + tid];
  }
  __syncthreads();

  float xv[HH];
#pragma unroll
  for (int k = 0; k < HH; ++k) xv[k] = ls[tid * HH + k];
  __syncthreads();

  unsigned short* __restrict__ lsh = (unsigned short*)ls;  // [256][66]
#pragma unroll 1
  for (int g = 0; g < NG; ++g) {
    float a = bih[g] + ((g < 2 * HH) ? bhh[g] : 0.0f);
#pragma unroll
    for (int k = 0; k < HH; ++k) a = fmaf(xv[k], Wih[g * HH + k], a);
    a *= (g < 2 * HH) ? -L2E : (2.0f * L2E);
    lsh[tid * 66 + g] = f2h(a);
  }
#pragma unroll
  for (int g = NG; g < SL; ++g) lsh[tid * 66 + g] = 0;
  __syncthreads();

  const unsigned* __restrict__ lsd = (const unsigned*)ls;
  unsigned* __restrict__ xgd = (unsigned*)xg;
#pragma unroll
  for (int i = 0; i < 32; ++i) {
    const int D = tid + i * 256;
    xgd[pair0 * 32 + D] = lsd[(D >> 5) * 33 + (D & 31)];
  }
}

// ---------------- K2: recurrence, dual-dot n-lanes, permlane-only ---------
// lanes 0-18: dotA = r-row i, own h_i.  lanes 32-50: dotA = n-row (38+i),
// dotB = z-row (19+i) — the n-lane computes BOTH n_i and z_i.
// Cross-lane per step: LOBCAST(r_i -> n-lanes), HIBCAST(nn), HIBCAST(zz).
// NO ds_bpermute -> zero bank conflicts, clean lgkm (write+3 reads only).
// h broadcast f16 via LDS (2B write, b128+b128+b64 reads); oproj lag-1 via
// dot2 on the old broadcast regs as filler inside the LDS turnaround.
__global__ void __launch_bounds__(64)
__attribute__((amdgpu_waves_per_eu(1, 1)))
gru_rec7(const unsigned short* __restrict__ xg, const float* __restrict__ Whh,
         const float* __restrict__ bhh, const float* __restrict__ Wout,
         const float* __restrict__ bout, float* __restrict__ out)
{
  __shared__ __align__(16) unsigned short hsh16[64];
  const int b = blockIdx.x;
  const int lane = threadIdx.x;
  const float L2E = 1.4426950408889634f;

  const int i19 = (lane & 31) < HH ? (lane & 31) : HH - 1;  // 0..18
  const bool up = lane >= 32;
  // dotA row: r-row i (low half) | n-row 38+i (high half)
  const int rowA = up ? (2 * HH + i19) : i19;
  // dotB row: z-row 19+i (used on n-lanes; dup elsewhere)
  const int rowB = HH + i19;
  const float sA = up ? (2.0f * L2E) : -L2E;

  v2h wA16[10], wB16[10], wo16[10];
#pragma unroll
  for (int j = 0; j < 10; ++j) {
    const int k0 = 2 * j, k1 = 2 * j + 1;
    wA16[j].x = (_Float16)(sA * Whh[rowA * HH + k0]);
    wA16[j].y = (_Float16)((k1 < HH) ? sA * Whh[rowA * HH + k1] : 0.0f);
    wB16[j].x = (_Float16)(-L2E * Whh[rowB * HH + k0]);
    wB16[j].y = (_Float16)((k1 < HH) ? -L2E * Whh[rowB * HH + k1] : 0.0f);
    wo16[j].x = (_Float16)Wout[k0];
    wo16[j].y = (_Float16)((k1 < HH) ? Wout[k1] : 0.0f);
  }
  const float dinitA = up ? (2.0f * L2E * bhh[rowA]) : 0.0f;  // n keeps bhn inside r*()
  const float bo = bout[0];

#if HAVE_PLS
  bool loIsX;
  {
    unsigned l = (unsigned)lane;
    u2 pr = __builtin_amdgcn_permlane32_swap(l, l, false, false);
    loIsX = ((unsigned)__builtin_amdgcn_readlane((int)pr.x, 32) < 32u);
  }
#define LOBCAST(val, dst) do { u2 _s = pls(val);                        \
    dst = __uint_as_float(loIsX ? _s.x : _s.y); } while (0)
#define HIBCAST(val, dst) do { u2 _s = pls(val);                        \
    dst = __uint_as_float(loIsX ? _s.y : _s.x); } while (0)
#else
  const int loaddr = (lane & 31) * 4;
  const int hiaddr = ((lane & 31) | 32) * 4;
#define LOBCAST(val, dst) dst = __uint_as_float((unsigned)              \
    __builtin_amdgcn_ds_bpermute(loaddr, (int)__float_as_uint(val)))
#define HIBCAST(val, dst) dst = __uint_as_float((unsigned)              \
    __builtin_amdgcn_ds_bpermute(hiaddr, (int)__float_as_uint(val)))
#endif

  float h = 0.0f;   // lane i<19 owns h_i (f32); broadcast copy is f16

  // xg slot addresses: A = rowA, B = rowB (z) — B used on n-lanes only
  const unsigned short* __restrict__ xbA = xg + (size_t)b * SL + rowA;
  const unsigned short* __restrict__ xbB = xg + (size_t)b * SL + rowB;
#define LOADA(dst, t) do { dst = xbA[(size_t)(t) * (NB * SL)]; } while (0)
#define LOADB(dst, t) do { dst = xbB[(size_t)(t) * (NB * SL)]; } while (0)

  unsigned short a0,a1,a2,a3,a4,a5,a6,a7, b0,b1,b2,b3,b4,b5,b6,b7;
  LOADA(a0,0); LOADB(b0,0); LOADA(a1,1); LOADB(b1,1);
  LOADA(a2,2); LOADB(b2,2); LOADA(a3,3); LOADB(b3,3);
  LOADA(a4,4); LOADB(b4,4); LOADA(a5,5); LOADB(b5,5);
  LOADA(a6,6); LOADB(b6,6); LOADA(a7,7); LOADB(b7,7);

  // double-buffered packed f16 h_{t-1}: P=h0..7, R=h8..15, Q=h16..18+pad
  u32x4 Pa = {0,0,0,0}, Ra = {0,0,0,0}, Pb, Rb;
  u32x2 Qa = {0,0}, Qb;

#define OPROJ16(Pi, Ri, Qi, ovar) do {                                  \
    float _o0 = bo, _o1 = 0.0f;                                         \
    _o0 = dot2h(wo16[0], Pi.x, _o0); _o1 = dot2h(wo16[1], Pi.y, _o1);   \
    _o0 = dot2h(wo16[2], Pi.z, _o0); _o1 = dot2h(wo16[3], Pi.w, _o1);   \
    _o0 = dot2h(wo16[4], Ri.x, _o0); _o1 = dot2h(wo16[5], Ri.y, _o1);   \
    _o0 = dot2h(wo16[6], Ri.z, _o0); _o1 = dot2h(wo16[7], Ri.w, _o1);   \
    _o0 = dot2h(wo16[8], Qi.x, _o0); _o1 = dot2h(wo16[9], Qi.y, _o1);   \
    ovar = _o0 + _o1;                                                   \
  } while (0)

#define BODY(tcur, sa, sb, Pi, Ri, Qi, Po, Ro, Qo, ovar) do {           \
    /* dotA: r-row (low) | n-row (high); dotB: z-row (high) */          \
    float _a0 = dinitA, _a1 = 0.0f;                                     \
    _a0 = dot2h(wA16[0], Pi.x, _a0); _a1 = dot2h(wA16[1], Pi.y, _a1);   \
    _a0 = dot2h(wA16[2], Pi.z, _a0); _a1 = dot2h(wA16[3], Pi.w, _a1);   \
    _a0 = dot2h(wA16[4], Ri.x, _a0); _a1 = dot2h(wA16[5], Ri.y, _a1);   \
    _a0 = dot2h(wA16[6], Ri.z, _a0); _a1 = dot2h(wA16[7], Ri.w, _a1);   \
    _a0 = dot2h(wA16[8], Qi.x, _a0); _a1 = dot2h(wA16[9], Qi.y, _a1);   \
    const float xvB = h2f(sb);                                          \
    float _b0 = xvB, _b1 = 0.0f;                                        \
    _b0 = dot2h(wB16[0], Pi.x, _b0); _b1 = dot2h(wB16[1], Pi.y, _b1);   \
    _b0 = dot2h(wB16[2], Pi.z, _b0); _b1 = dot2h(wB16[3], Pi.w, _b1);   \
    _b0 = dot2h(wB16[4], Ri.x, _b0); _b1 = dot2h(wB16[5], Ri.y, _b1);   \
    _b0 = dot2h(wB16[6], Ri.z, _b0); _b1 = dot2h(wB16[7], Ri.w, _b1);   \
    _b0 = dot2h(wB16[8], Qi.x, _b0); _b1 = dot2h(wB16[9], Qi.y, _b1);   \
    const float preA = _a0 + _a1;          /* r h-dot | n h-dot+bhn */  \
    const float xvA = h2f(sa);                                          \
    const float sigA = frcp(fexp2(xvA + preA) + 1.0f);  /* r_i (low) */ \
    float rr; LOBCAST(sigA, rr);           /* r_i -> n-lanes */         \
    const float preB = _b0 + _b1;                                       \
    const float zzN = frcp(fexp2(preB) + 1.0f);   /* z_i on n-lane */   \
    const float arg = fmaf(rr, preA, xvA);                              \
    const float nnN = fmaf(-2.0f, frcp(fexp2(arg) + 1.0f), 1.0f);       \
    float nh; HIBCAST(nnN, nh);            /* n_i -> h-lanes */         \
    float zh; HIBCAST(zzN, zh);            /* z_i -> h-lanes */         \
    h = fmaf(zh, h - nh, nh);                                           \
    /* broadcast h_t as f16 (pad lanes bounded; weights zero them) */   \
    hsh16[lane] = f2h(h);                                               \
    Po = *(const u32x4*)&hsh16[0];                                      \
    Ro = *(const u32x4*)&hsh16[8];                                      \
    Qo = *(const u32x2*)&hsh16[16];                                     \
    /* filler under LDS turnaround: oproj(h_{t-1}) + prefetch */        \
    OPROJ16(Pi, Ri, Qi, ovar);                                          \
    { const int _tl = ((tcur) + 8 < TT) ? (tcur) + 8 : TT - 1;          \
      LOADA(sa, _tl); LOADB(sb, _tl); }                                 \
  } while (0)

  float o0, o1, o2, o3, o4, o5, o6, o7;
  float* __restrict__ ob = out + b;

  for (int t = 0; t < TT; t += 8) {
    BODY(t + 0, a0, b0, Pa, Ra, Qa, Pb, Rb, Qb, o0);
    BODY(t + 1, a1, b1, Pb, Rb, Qb, Pa, Ra, Qa, o1);
    BODY(t + 2, a2, b2, Pa, Ra, Qa, Pb, Rb, Qb, o2);
    BODY(t + 3, a3, b3, Pb, Rb, Qb, Pa, Ra, Qa, o3);
    BODY(t + 4, a4, b4, Pa, Ra, Qa, Pb, Rb, Qb, o4);
    BODY(t + 5, a5, b5, Pb, Rb, Qb, Pa, Ra, Qa, o5);
    BODY(t + 6, a6, b6, Pa, Ra, Qa, Pb, Rb, Qb, o6);
    BODY(t + 7, a7, b7, Pb, Rb, Qb, Pa, Ra, Qa, o7);
    if (lane == 0) {
      ob[(size_t)((t > 0) ? t - 1 : 0) * NB] = o0;  // junk@t=0, overwritten
      ob[(size_t)(t + 0) * NB] = o1;
      ob[(size_t)(t + 1) * NB] = o2;
      ob[(size_t)(t + 2) * NB] = o3;
      ob[(size_t)(t + 3) * NB] = o4;
      ob[(size_t)(t + 4) * NB] = o5;
      ob[(size_t)(t + 5) * NB] = o6;
      ob[(size_t)(t + 6) * NB] = o7;
    }
  }

  // epilogue: out[TT-1] from the final broadcast (state ended in Pa/Ra/Qa)
  {
    float oe;
    OPROJ16(Pa, Ra, Qa, oe);
    if (lane == 0) ob[(size_t)(TT - 1) * NB] = oe;
  }

#undef LOADA
#undef LOADB
#undef BODY
#undef OPROJ16
#undef LOBCAST
#undef HIBCAST
}

// ---------------- Fallback: round-8 fused kernel (proven, 555us) ----------
__global__ void __launch_bounds__(64)
__attribute__((amdgpu_waves_per_eu(1, 1)))
gru57_v4(const float* __restrict__ x, const float* __restrict__ Wih,
         const float* __restrict__ Whh, const float* __restrict__ bih,
         const float* __restrict__ bhh, const float* __restrict__ Wout,
         const float* __restrict__ bout, float* __restrict__ out)
{
  const int b = blockIdx.x;
  const int lane = threadIdx.x;
  const float L2E = 1.4426950408889634f;

  int row;
  if (lane < 32)      row = lane;
  else if (lane < 51) row = lane + 6;
  else if (lane < 57) row = lane - 19;
  else                row = 37;
  const bool isn = (row >= 2 * HH);
  const float scale = isn ? (2.0f * L2E) : L2E;

  v2f wx2[10], wh2[10], wo2[10];
#pragma unroll
  for (int j = 0; j < 10; ++j) {
    const int k0 = 2 * j, k1 = 2 * j + 1;
    wx2[j].x = Wih[row * HH + k0] * scale;
    wx2[j].y = (k1 < HH) ? Wih[row * HH + k1] * scale : 0.0f;
    wh2[j].x = Whh[row * HH + k0] * scale;
    wh2[j].y = (k1 < HH) ? Whh[row * HH + k1] * scale : 0.0f;
    wo2[j].x = Wout[k0];
    wo2[j].y = (k1 < HH) ? Wout[k1] : 0.0f;
  }
  const float bxv = bih[row] * scale, bhv = bhh[row] * scale;
  const float ax0 = isn ? bxv : (bxv + bhv);
  const float ah0 = isn ? bhv : 0.0f;
  const float bo  = bout[0];

  const int il = lane < HH ? lane : HH - 1;
  const int zaddr = ((il < 13) ? (19 + il) : (38 + il)) * 4;

#if HAVE_PLS
  bool loIsX;
  {
    unsigned l = (unsigned)lane;
    u2 pr = __builtin_amdgcn_permlane32_swap(l, l, false, false);
    loIsX = ((unsigned)__builtin_amdgcn_readlane((int)pr.x, 32) < 32u);
  }
#define LOBCAST(val, dst) do { u2 _s = pls(val);                        \
    dst = __uint_as_float(loIsX ? _s.x : _s.y); } while (0)
#define HIBCAST(val, dst) do { u2 _s = pls(val);                        \
    dst = __uint_as_float(loIsX ? _s.y : _s.x); } while (0)
#else
  const int loaddr = (lane & 31) * 4;
  const int hiaddr = ((lane & 31) | 32) * 4;
#define LOBCAST(val, dst) dst = __uint_as_float((unsigned)              \
    __builtin_amdgcn_ds_bpermute(loaddr, (int)__float_as_uint(val)))
#define HIBCAST(val, dst) dst = __uint_as_float((unsigned)              \
    __builtin_amdgcn_ds_bpermute(hiaddr, (int)__float_as_uint(val)))
#endif

  float h = 0.0f;
  v2f sh2[10];
#pragma unroll
  for (int j = 0; j < 10; ++j) sh2[j] = mk2(0.f, 0.f);

  const int kx = lane < HH ? lane : HH - 1;
  const float* __restrict__ xbase = x + (size_t)b * HH + kx;

#define LOADXF(dst, trow) do { dst = xbase[(size_t)(trow) * (NB * HH)]; } while (0)
#define XBCAST(slot, xu) do {                                           \
    _Pragma("unroll")                                                   \
    for (int _j = 0; _j < 9; ++_j) {                                    \
      xu[_j].x = rlf(slot, 2 * _j);                                     \
      xu[_j].y = rlf(slot, 2 * _j + 1);                                 \
    }                                                                   \
    xu[9].x = rlf(slot, 18); xu[9].y = 0.0f;                            \
  } while (0)
#define XDOT(xu, dstvar) do {                                           \
    v2f _aA = mk2(ax0, 0.0f), _aB = mk2(0.0f, 0.0f);                    \
    _Pragma("unroll")                                                   \
    for (int _j = 0; _j < 5; ++_j)  _aA = vfma(xu[_j], wx2[_j], _aA);   \
    _Pragma("unroll")                                                   \
    for (int _j = 5; _j < 10; ++_j) _aB = vfma(xu[_j], wx2[_j], _aB);   \
    const v2f _s = _aA + _aB;                                           \
    dstvar = _s.x + _s.y;                                               \
  } while (0)

  float xlA, xlB, xlC, xlD;
  LOADXF(xlA, 0); LOADXF(xlB, 1); LOADXF(xlC, 2); LOADXF(xlD, 3);
  float prex;
  { v2f xu0[10]; XBCAST(xlA, xu0); XDOT(xu0, prex); }

#define BODYF(tcur, nslot, lslot) do {                                  \
    v2f ahA = mk2(ah0, 0.0f), ahB = mk2(0.0f, 0.0f);                    \
    _Pragma("unroll")                                                   \
    for (int _j = 0; _j < 5; ++_j)  ahA = vfma(sh2[_j], wh2[_j], ahA);  \
    _Pragma("unroll")                                                   \
    for (int _j = 5; _j < 10; ++_j) ahB = vfma(sh2[_j], wh2[_j], ahB);  \
    float prexN;                                                        \
    { v2f _xu[10]; XBCAST(nslot, _xu); XDOT(_xu, prexN); }              \
    { const int _tl = ((tcur) + 4 < TT) ? (tcur) + 4 : TT - 1;          \
      LOADXF(lslot, _tl); }                                             \
    const v2f ahv = ahA + ahB;                                          \
    const float preh = ahv.x + ahv.y;                                   \
    const float pre  = prex + preh;                                     \
    const float sig  = frcp(1.0f + fexp2(-pre));                        \
    const int zzi = __builtin_amdgcn_ds_bpermute(                       \
        zaddr, (int)__float_as_uint(sig));                              \
    float rr; LOBCAST(sig, rr);                                         \
    const float npre = fmaf(rr, preh, prex);                            \
    const float nn = fmaf(-2.0f, frcp(fexp2(npre) + 1.0f), 1.0f);       \
    float nh; HIBCAST(nn, nh);                                          \
    const float zz = __uint_as_float((unsigned)zzi);                    \
    h = fmaf(zz, h - nh, nh);                                           \
    _Pragma("unroll")                                                   \
    for (int _j = 0; _j < 9; ++_j) {                                    \
      sh2[_j].x = rlf(h, 2 * _j);                                       \
      sh2[_j].y = rlf(h, 2 * _j + 1);                                   \
    }                                                                   \
    sh2[9].x = rlf(h, 18); sh2[9].y = 0.0f;                             \
    v2f oA = mk2(bo, 0.0f), oB = mk2(0.0f, 0.0f);                       \
    _Pragma("unroll")                                                   \
    for (int _j = 0; _j < 5; ++_j)  oA = vfma(sh2[_j], wo2[_j], oA);    \
    _Pragma("unroll")                                                   \
    for (int _j = 5; _j < 10; ++_j) oB = vfma(sh2[_j], wo2[_j], oB);    \
    const v2f ov = oA + oB;                                             \
    if (lane == 0) out[(size_t)(tcur) * NB + b] = ov.x + ov.y;          \
    prex = prexN;                                                       \
  } while (0)

  for (int t = 0; t < TT; t += 4) {
    BODYF(t + 0, xlB, xlA);
    BODYF(t + 1, xlC, xlB);
    BODYF(t + 2, xlD, xlC);
    BODYF(t + 3, xlA, xlD);
  }

#undef LOADXF
#undef XBCAST
#undef XDOT
#undef BODYF
#undef LOBCAST
#undef HIBCAST
}

extern "C" void kernel_launch(void* const* d_in, const int* in_sizes, int n_in,
                              void* d_out, int out_size, void* d_ws, size_t ws_size,
                              hipStream_t stream) {
  const float* x    = (const float*)d_in[0];
  const float* Wih  = (const float*)d_in[1];
  const float* Whh  = (const float*)d_in[2];
  const float* bih  = (const float*)d_in[3];
  const float* bhh  = (const float*)d_in[4];
  const float* Wout = (const float*)d_in[5];
  const float* bout = (const float*)d_in[6];
  float* out = (float*)d_out;

  const size_t need = (size_t)TT * NB * SL * sizeof(unsigned short);  // 256MB
  if (ws_size >= need) {
    unsigned short* xgws = (unsigned short*)d_ws;
    xg_proj4<<<dim3((TT * NB) / 256), dim3(256), 0, stream>>>(
        x, Wih, bih, bhh, xgws);
    gru_rec7<<<dim3(NB), dim3(64), 0, stream>>>(
        xgws, Whh, bhh, Wout, bout, out);
  } else {
    gru57_v4<<<dim3(NB), dim3(64), 0, stream>>>(
        x, Wih, Whh, bih, bhh, Wout, bout, out);
  }
}

// Round 15
// 524.812 us; speedup vs baseline: 1.1123x; 1.1123x over previous
//
#include <hip/hip_runtime.h>
#include <math.h>

#define HH 19
#define NG 57
#define SL 64        // padded slots per xg row (128B line)
#define NB 1024
#define TT 2048

typedef float v2f __attribute__((ext_vector_type(2)));
typedef unsigned u2 __attribute__((ext_vector_type(2)));
typedef unsigned u32x4 __attribute__((ext_vector_type(4)));
typedef unsigned u32x2 __attribute__((ext_vector_type(2)));
typedef _Float16 v2h __attribute__((ext_vector_type(2)));

__device__ __forceinline__ float rlf(float v, int l) {
  return __uint_as_float(__builtin_amdgcn_readlane(__float_as_uint(v), l));
}
__device__ __forceinline__ float frcp(float v) { return __builtin_amdgcn_rcpf(v); }
__device__ __forceinline__ float fexp2(float v) {
#if __has_builtin(__builtin_amdgcn_exp2f)
  return __builtin_amdgcn_exp2f(v);
#else
  return exp2f(v);
#endif
}
__device__ __forceinline__ unsigned short f2h(float f) {
  return __builtin_bit_cast(unsigned short, (_Float16)f);
}
__device__ __forceinline__ float h2f(unsigned short u) {
  return (float)__builtin_bit_cast(_Float16, u);
}
__device__ __forceinline__ v2f mk2(float a, float b) { v2f r; r.x = a; r.y = b; return r; }
__device__ __forceinline__ v2f vfma(v2f a, v2f b, v2f c) {
#if __has_builtin(__builtin_elementwise_fma)
  return __builtin_elementwise_fma(a, b, c);
#else
  v2f r; r.x = fmaf(a.x, b.x, c.x); r.y = fmaf(a.y, b.y, c.y); return r;
#endif
}

// v_dot2_f32_f16: w.x*d.lo + w.y*d.hi + acc (f32 accumulate, full rate)
#if __has_builtin(__builtin_amdgcn_fdot2)
__device__ __forceinline__ float dot2h(v2h w, unsigned d, float acc) {
  return __builtin_amdgcn_fdot2(w, __builtin_bit_cast(v2h, d), acc, false);
}
#else
__device__ __forceinline__ float dot2h(v2h w, unsigned d, float acc) {
  const float fl = h2f((unsigned short)(d & 0xffffu));
  const float fh = h2f((unsigned short)(d >> 16));
  return fmaf((float)w.x, fl, fmaf((float)w.y, fh, acc));
}
#endif

#if __has_builtin(__builtin_amdgcn_permlane32_swap)
#define HAVE_PLS 1
__device__ __forceinline__ u2 pls(float x) {
  unsigned u = __float_as_uint(x);
  return __builtin_amdgcn_permlane32_swap(u, u, false, false);
}
#else
#define HAVE_PLS 0
#endif

// ---------------- K0: weight repack (one-time, trivial) --------------------
// wp[g][20]: cols 0-18 = scale_g * Wih[g], col 19 = scale_g * (bih+maybe bhh).
// 20-float rows -> every row 8B-aligned so K1 can use pk_fma with uniform
// 64-bit weight operands.
__global__ __launch_bounds__(64) void wpack(
    const float* __restrict__ Wih, const float* __restrict__ bih,
    const float* __restrict__ bhh, float* __restrict__ wp)
{
  const int t = threadIdx.x + blockIdx.x * 64;
  if (t < NG * 20) {
    const int g = t / 20, k = t - g * 20;
    const float L2E = 1.4426950408889634f;
    const float s = (g < 2 * HH) ? -L2E : 2.0f * L2E;
    wp[t] = (k < HH) ? Wih[g * HH + k] * s
                     : (bih[g] + (g < 2 * HH ? bhh[g] : 0.0f)) * s;
  }
}

// ---------------- K1: x-projection, pk_fma gate loop -----------------------
// Same layout/IO as xg_proj4 (proven), but the 19-fma gate dot becomes
// 10 v_pk_fma_f32 against the aligned wp rows (uniform loads).
__global__ __launch_bounds__(256) void xg_proj5(
    const float* __restrict__ x, const float* __restrict__ wp,
    unsigned short* __restrict__ xg)
{
  __shared__ __align__(16) float ls[256 * 33];
  const int tid = threadIdx.x;
  const size_t pair0 = (size_t)blockIdx.x * 256;

  {
    const float* __restrict__ src = x + pair0 * HH;
#pragma unroll
    for (int j = 0; j < HH; ++j) ls[j * 256 + tid] = src[j * 256 + tid];
  }
  __syncthreads();

  v2f xv2[10];
#pragma unroll
  for (int j = 0; j < 9; ++j)
    xv2[j] = mk2(ls[tid * HH + 2 * j], ls[tid * HH + 2 * j + 1]);
  xv2[9] = mk2(ls[tid * HH + 18], 0.0f);
  __syncthreads();

  unsigned short* __restrict__ lsh = (unsigned short*)ls;  // [256][66]
#pragma unroll 1
  for (int g = 0; g < NG; ++g) {
    const v2f* __restrict__ wr = (const v2f*)(wp + g * 20);  // 8B-aligned
    v2f a0 = mk2(wp[g * 20 + HH], 0.0f), a1 = mk2(0.0f, 0.0f);
#pragma unroll
    for (int j = 0; j < 5; ++j)  a0 = vfma(xv2[j], wr[j], a0);
#pragma unroll
    for (int j = 5; j < 10; ++j) a1 = vfma(xv2[j], wr[j], a1);
    const v2f sv = a0 + a1;
    lsh[tid * 66 + g] = f2h(sv.x + sv.y);
  }
#pragma unroll
  for (int g = NG; g < SL; ++g) lsh[tid * 66 + g] = 0;
  __syncthreads();

  const unsigned* __restrict__ lsd = (const unsigned*)ls;
  unsigned* __restrict__ xgd = (unsigned*)xg;
#pragma unroll
  for (int i = 0; i < 32; ++i) {
    const int D = tid + i * 256;
    xgd[pair0 * 32 + D] = lsd[(D >> 5) * 33 + (D & 31)];
  }
}

// ---------------- K2: recurrence, oproj as lane-57 SIMT row ----------------
// rec6 structure (measured 435us) with the out-projection folded into the
// existing h-dot: lane 57's weight row = Wout (unscaled), dinit = bo, so its
// preh IS out[t-1]. Removes 11 oproj instrs + wo16 regs at zero added work.
// Lane 57's activation path computes bounded junk; its broadcast slot (57)
// is never read (reads cover shorts 0..19 only).
__global__ void __launch_bounds__(64)
__attribute__((amdgpu_waves_per_eu(1, 1)))
gru_rec8(const unsigned short* __restrict__ xg, const float* __restrict__ Whh,
         const float* __restrict__ bhh, const float* __restrict__ Wout,
         const float* __restrict__ bout, float* __restrict__ out)
{
  __shared__ __align__(16) unsigned short hsh16[64];
  const int b = blockIdx.x;
  const int lane = threadIdx.x;
  const float L2E = 1.4426950408889634f;

  int row;
  if (lane < 32)      row = lane;          // r 0-18 (h owners), z 19-31
  else if (lane < 51) row = lane + 6;      // n 38-56
  else if (lane < 57) row = lane - 19;     // z 32-37
  else                row = 37;            // dup (lane 57 overridden below)
  const bool isn = (row >= 2 * HH);
  const bool isO = (lane == 57);           // oproj rider lane
  const float s = isn ? (2.0f * L2E) : -L2E;

  v2h wh16[10];
#pragma unroll
  for (int j = 0; j < 10; ++j) {
    const int k0 = 2 * j, k1 = 2 * j + 1;
    const float w0 = isO ? Wout[k0] : s * Whh[row * HH + k0];
    const float w1 = (k1 < HH) ? (isO ? Wout[k1] : s * Whh[row * HH + k1]) : 0.0f;
    wh16[j].x = (_Float16)w0;
    wh16[j].y = (_Float16)w1;
  }
  const float dinit = isO ? bout[0] : (isn ? (2.0f * L2E * bhh[row]) : 0.0f);

  const int il = lane < HH ? lane : HH - 1;
  const int zaddr = ((il < 13) ? (19 + il) : (38 + il)) * 4;

#if HAVE_PLS
  bool loIsX;
  {
    unsigned l = (unsigned)lane;
    u2 pr = __builtin_amdgcn_permlane32_swap(l, l, false, false);
    loIsX = ((unsigned)__builtin_amdgcn_readlane((int)pr.x, 32) < 32u);
  }
#define LOBCAST(val, dst) do { u2 _s = pls(val);                        \
    dst = __uint_as_float(loIsX ? _s.x : _s.y); } while (0)
#define HIBCAST(val, dst) do { u2 _s = pls(val);                        \
    dst = __uint_as_float(loIsX ? _s.y : _s.x); } while (0)
#else
  const int loaddr = (lane & 31) * 4;
  const int hiaddr = ((lane & 31) | 32) * 4;
#define LOBCAST(val, dst) dst = __uint_as_float((unsigned)              \
    __builtin_amdgcn_ds_bpermute(loaddr, (int)__float_as_uint(val)))
#define HIBCAST(val, dst) dst = __uint_as_float((unsigned)              \
    __builtin_amdgcn_ds_bpermute(hiaddr, (int)__float_as_uint(val)))
#endif

  float h = 0.0f;     // lane i<19 owns h_i (f32); broadcast copy is f16

  const unsigned short* __restrict__ xb = xg + (size_t)b * SL + row;
#define LOADX(dst, trow) do { dst = xb[(size_t)(trow) * (NB * SL)]; } while (0)

  unsigned short s0, s1, s2, s3, s4, s5, s6, s7;
  LOADX(s0, 0); LOADX(s1, 1); LOADX(s2, 2); LOADX(s3, 3);
  LOADX(s4, 4); LOADX(s5, 5); LOADX(s6, 6); LOADX(s7, 7);

  // double-buffered packed h_{t-1}: P=h0..7, R=h8..15, Q=h16..18+pad
  u32x4 Pa = {0,0,0,0}, Ra = {0,0,0,0}, Pb, Rb;
  u32x2 Qa = {0,0}, Qb;

#define HDOT(Pi, Ri, Qi, dstvar) do {                                   \
    float _a0 = dinit, _a1 = 0.0f;                                      \
    _a0 = dot2h(wh16[0], Pi.x, _a0); _a1 = dot2h(wh16[1], Pi.y, _a1);   \
    _a0 = dot2h(wh16[2], Pi.z, _a0); _a1 = dot2h(wh16[3], Pi.w, _a1);   \
    _a0 = dot2h(wh16[4], Ri.x, _a0); _a1 = dot2h(wh16[5], Ri.y, _a1);   \
    _a0 = dot2h(wh16[6], Ri.z, _a0); _a1 = dot2h(wh16[7], Ri.w, _a1);   \
    _a0 = dot2h(wh16[8], Qi.x, _a0); _a1 = dot2h(wh16[9], Qi.y, _a1);   \
    dstvar = _a0 + _a1;                                                 \
  } while (0)

#define BODY(tcur, slot, Pi, Ri, Qi, Po, Ro, Qo, ovar) do {             \
    float preh; HDOT(Pi, Ri, Qi, preh);                                 \
    ovar = preh;                 /* lane 57: = out[t-1] (bo included) */ \
    const float xv = h2f(slot);                                         \
    const float pre = xv + preh;                                        \
    const float sig = frcp(fexp2(pre) + 1.0f);                          \
    const int zzi = __builtin_amdgcn_ds_bpermute(                       \
        zaddr, (int)__float_as_uint(sig));                              \
    float rr; LOBCAST(sig, rr);                                         \
    const float arg = fmaf(rr, preh, xv);                               \
    const float nn = fmaf(-2.0f, frcp(fexp2(arg) + 1.0f), 1.0f);        \
    float nh; HIBCAST(nn, nh);                                          \
    const float zz = __uint_as_float((unsigned)zzi);                    \
    h = fmaf(zz, h - nh, nh);                                           \
    hsh16[lane] = f2h(h);                                               \
    Po = *(const u32x4*)&hsh16[0];                                      \
    Ro = *(const u32x4*)&hsh16[8];                                      \
    Qo = *(const u32x2*)&hsh16[16];                                     \
    { const int _tl = ((tcur) + 8 < TT) ? (tcur) + 8 : TT - 1;          \
      LOADX(slot, _tl); }                                               \
  } while (0)

  float o0, o1, o2, o3, o4, o5, o6, o7;
  float* __restrict__ ob = out + b;

  for (int t = 0; t < TT; t += 8) {
    BODY(t + 0, s0, Pa, Ra, Qa, Pb, Rb, Qb, o0);
    BODY(t + 1, s1, Pb, Rb, Qb, Pa, Ra, Qa, o1);
    BODY(t + 2, s2, Pa, Ra, Qa, Pb, Rb, Qb, o2);
    BODY(t + 3, s3, Pb, Rb, Qb, Pa, Ra, Qa, o3);
    BODY(t + 4, s4, Pa, Ra, Qa, Pb, Rb, Qb, o4);
    BODY(t + 5, s5, Pb, Rb, Qb, Pa, Ra, Qa, o5);
    BODY(t + 6, s6, Pa, Ra, Qa, Pb, Rb, Qb, o6);
    BODY(t + 7, s7, Pb, Rb, Qb, Pa, Ra, Qa, o7);
    if (lane == 57) {
      ob[(size_t)((t > 0) ? t - 1 : 0) * NB] = o0;  // junk@t=0, overwritten
      ob[(size_t)(t + 0) * NB] = o1;
      ob[(size_t)(t + 1) * NB] = o2;
      ob[(size_t)(t + 2) * NB] = o3;
      ob[(size_t)(t + 3) * NB] = o4;
      ob[(size_t)(t + 4) * NB] = o5;
      ob[(size_t)(t + 5) * NB] = o6;
      ob[(size_t)(t + 6) * NB] = o7;
    }
  }

  // epilogue: out[TT-1] = lane 57's dot on the final broadcast (Pa/Ra/Qa)
  {
    float oe; HDOT(Pa, Ra, Qa, oe);
    if (lane == 57) ob[(size_t)(TT - 1) * NB] = oe;
  }

#undef LOADX
#undef BODY
#undef HDOT
#undef LOBCAST
#undef HIBCAST
}

// ---------------- Fallback: round-8 fused kernel (proven, 555us) ----------
__global__ void __launch_bounds__(64)
__attribute__((amdgpu_waves_per_eu(1, 1)))
gru57_v4(const float* __restrict__ x, const float* __restrict__ Wih,
         const float* __restrict__ Whh, const float* __restrict__ bih,
         const float* __restrict__ bhh, const float* __restrict__ Wout,
         const float* __restrict__ bout, float* __restrict__ out)
{
  const int b = blockIdx.x;
  const int lane = threadIdx.x;
  const float L2E = 1.4426950408889634f;

  int row;
  if (lane < 32)      row = lane;
  else if (lane < 51) row = lane + 6;
  else if (lane < 57) row = lane - 19;
  else                row = 37;
  const bool isn = (row >= 2 * HH);
  const float scale = isn ? (2.0f * L2E) : L2E;

  v2f wx2[10], wh2[10], wo2[10];
#pragma unroll
  for (int j = 0; j < 10; ++j) {
    const int k0 = 2 * j, k1 = 2 * j + 1;
    wx2[j].x = Wih[row * HH + k0] * scale;
    wx2[j].y = (k1 < HH) ? Wih[row * HH + k1] * scale : 0.0f;
    wh2[j].x = Whh[row * HH + k0] * scale;
    wh2[j].y = (k1 < HH) ? Whh[row * HH + k1] * scale : 0.0f;
    wo2[j].x = Wout[k0];
    wo2[j].y = (k1 < HH) ? Wout[k1] : 0.0f;
  }
  const float bxv = bih[row] * scale, bhv = bhh[row] * scale;
  const float ax0 = isn ? bxv : (bxv + bhv);
  const float ah0 = isn ? bhv : 0.0f;
  const float bo  = bout[0];

  const int il = lane < HH ? lane : HH - 1;
  const int zaddr = ((il < 13) ? (19 + il) : (38 + il)) * 4;

#if HAVE_PLS
  bool loIsX;
  {
    unsigned l = (unsigned)lane;
    u2 pr = __builtin_amdgcn_permlane32_swap(l, l, false, false);
    loIsX = ((unsigned)__builtin_amdgcn_readlane((int)pr.x, 32) < 32u);
  }
#define LOBCAST(val, dst) do { u2 _s = pls(val);                        \
    dst = __uint_as_float(loIsX ? _s.x : _s.y); } while (0)
#define HIBCAST(val, dst) do { u2 _s = pls(val);                        \
    dst = __uint_as_float(loIsX ? _s.y : _s.x); } while (0)
#else
  const int loaddr = (lane & 31) * 4;
  const int hiaddr = ((lane & 31) | 32) * 4;
#define LOBCAST(val, dst) dst = __uint_as_float((unsigned)              \
    __builtin_amdgcn_ds_bpermute(loaddr, (int)__float_as_uint(val)))
#define HIBCAST(val, dst) dst = __uint_as_float((unsigned)              \
    __builtin_amdgcn_ds_bpermute(hiaddr, (int)__float_as_uint(val)))
#endif

  float h = 0.0f;
  v2f sh2[10];
#pragma unroll
  for (int j = 0; j < 10; ++j) sh2[j] = mk2(0.f, 0.f);

  const int kx = lane < HH ? lane : HH - 1;
  const float* __restrict__ xbase = x + (size_t)b * HH + kx;

#define LOADXF(dst, trow) do { dst = xbase[(size_t)(trow) * (NB * HH)]; } while (0)
#define XBCAST(slot, xu) do {                                           \
    _Pragma("unroll")                                                   \
    for (int _j = 0; _j < 9; ++_j) {                                    \
      xu[_j].x = rlf(slot, 2 * _j);                                     \
      xu[_j].y = rlf(slot, 2 * _j + 1);                                 \
    }                                                                   \
    xu[9].x = rlf(slot, 18); xu[9].y = 0.0f;                            \
  } while (0)
#define XDOT(xu, dstvar) do {                                           \
    v2f _aA = mk2(ax0, 0.0f), _aB = mk2(0.0f, 0.0f);                    \
    _Pragma("unroll")                                                   \
    for (int _j = 0; _j < 5; ++_j)  _aA = vfma(xu[_j], wx2[_j], _aA);   \
    _Pragma("unroll")                                                   \
    for (int _j = 5; _j < 10; ++_j) _aB = vfma(xu[_j], wx2[_j], _aB);   \
    const v2f _s = _aA + _aB;                                           \
    dstvar = _s.x + _s.y;                                               \
  } while (0)

  float xlA, xlB, xlC, xlD;
  LOADXF(xlA, 0); LOADXF(xlB, 1); LOADXF(xlC, 2); LOADXF(xlD, 3);
  float prex;
  { v2f xu0[10]; XBCAST(xlA, xu0); XDOT(xu0, prex); }

#define BODYF(tcur, nslot, lslot) do {                                  \
    v2f ahA = mk2(ah0, 0.0f), ahB = mk2(0.0f, 0.0f);                    \
    _Pragma("unroll")                                                   \
    for (int _j = 0; _j < 5; ++_j)  ahA = vfma(sh2[_j], wh2[_j], ahA);  \
    _Pragma("unroll")                                                   \
    for (int _j = 5; _j < 10; ++_j) ahB = vfma(sh2[_j], wh2[_j], ahB);  \
    float prexN;                                                        \
    { v2f _xu[10]; XBCAST(nslot, _xu); XDOT(_xu, prexN); }              \
    { const int _tl = ((tcur) + 4 < TT) ? (tcur) + 4 : TT - 1;          \
      LOADXF(lslot, _tl); }                                             \
    const v2f ahv = ahA + ahB;                                          \
    const float preh = ahv.x + ahv.y;                                   \
    const float pre  = prex + preh;                                     \
    const float sig  = frcp(1.0f + fexp2(-pre));                        \
    const int zzi = __builtin_amdgcn_ds_bpermute(                       \
        zaddr, (int)__float_as_uint(sig));                              \
    float rr; LOBCAST(sig, rr);                                         \
    const float npre = fmaf(rr, preh, prex);                            \
    const float nn = fmaf(-2.0f, frcp(fexp2(npre) + 1.0f), 1.0f);       \
    float nh; HIBCAST(nn, nh);                                          \
    const float zz = __uint_as_float((unsigned)zzi);                    \
    h = fmaf(zz, h - nh, nh);                                           \
    _Pragma("unroll")                                                   \
    for (int _j = 0; _j < 9; ++_j) {                                    \
      sh2[_j].x = rlf(h, 2 * _j);                                       \
      sh2[_j].y = rlf(h, 2 * _j + 1);                                   \
    }                                                                   \
    sh2[9].x = rlf(h, 18); sh2[9].y = 0.0f;                             \
    v2f oA = mk2(bo, 0.0f), oB = mk2(0.0f, 0.0f);                       \
    _Pragma("unroll")                                                   \
    for (int _j = 0; _j < 5; ++_j)  oA = vfma(sh2[_j], wo2[_j], oA);    \
    _Pragma("unroll")                                                   \
    for (int _j = 5; _j < 10; ++_j) oB = vfma(sh2[_j], wo2[_j], oB);    \
    const v2f ov = oA + oB;                                             \
    if (lane == 0) out[(size_t)(tcur) * NB + b] = ov.x + ov.y;          \
    prex = prexN;                                                       \
  } while (0)

  for (int t = 0; t < TT; t += 4) {
    BODYF(t + 0, xlB, xlA);
    BODYF(t + 1, xlC, xlB);
    BODYF(t + 2, xlD, xlC);
    BODYF(t + 3, xlA, xlD);
  }

#undef LOADXF
#undef XBCAST
#undef XDOT
#undef BODYF
#undef LOBCAST
#undef HIBCAST
}

extern "C" void kernel_launch(void* const* d_in, const int* in_sizes, int n_in,
                              void* d_out, int out_size, void* d_ws, size_t ws_size,
                              hipStream_t stream) {
  const float* x    = (const float*)d_in[0];
  const float* Wih  = (const float*)d_in[1];
  const float* Whh  = (const float*)d_in[2];
  const float* bih  = (const float*)d_in[3];
  const float* bhh  = (const float*)d_in[4];
  const float* Wout = (const float*)d_in[5];
  const float* bout = (const float*)d_in[6];
  float* out = (float*)d_out;

  const size_t xg_bytes = (size_t)TT * NB * SL * sizeof(unsigned short); // 256MB
  const size_t wp_bytes = (size_t)NG * 20 * sizeof(float);               // 4.6KB
  if (ws_size >= xg_bytes + wp_bytes) {
    unsigned short* xgws = (unsigned short*)d_ws;
    float* wpws = (float*)((char*)d_ws + xg_bytes);
    wpack<<<dim3((NG * 20 + 63) / 64), dim3(64), 0, stream>>>(
        Wih, bih, bhh, wpws);
    xg_proj5<<<dim3((TT * NB) / 256), dim3(256), 0, stream>>>(
        x, wpws, xgws);
    gru_rec8<<<dim3(NB), dim3(64), 0, stream>>>(
        xgws, Whh, bhh, Wout, bout, out);
  } else {
    gru57_v4<<<dim3(NB), dim3(64), 0, stream>>>(
        x, Wih, Whh, bih, bhh, Wout, bout, out);
  }
}

// Round 16
// 523.919 us; speedup vs baseline: 1.1142x; 1.0017x over previous
//
#include <hip/hip_runtime.h>
#include <math.h>

#define HH 19
#define NG 57
#define SL 64        // padded slots per xg row (128B line)
#define NB 1024
#define TT 2048

typedef float v2f __attribute__((ext_vector_type(2)));
typedef unsigned u2 __attribute__((ext_vector_type(2)));
typedef unsigned u32x4 __attribute__((ext_vector_type(4)));
typedef unsigned u32x2 __attribute__((ext_vector_type(2)));
typedef _Float16 v2h __attribute__((ext_vector_type(2)));

__device__ __forceinline__ float rlf(float v, int l) {
  return __uint_as_float(__builtin_amdgcn_readlane(__float_as_uint(v), l));
}
__device__ __forceinline__ float frcp(float v) { return __builtin_amdgcn_rcpf(v); }
__device__ __forceinline__ float fexp2(float v) {
#if __has_builtin(__builtin_amdgcn_exp2f)
  return __builtin_amdgcn_exp2f(v);
#else
  return exp2f(v);
#endif
}
__device__ __forceinline__ unsigned short f2h(float f) {
  return __builtin_bit_cast(unsigned short, (_Float16)f);
}
__device__ __forceinline__ float h2f(unsigned short u) {
  return (float)__builtin_bit_cast(_Float16, u);
}
__device__ __forceinline__ v2f mk2(float a, float b) { v2f r; r.x = a; r.y = b; return r; }
__device__ __forceinline__ v2f vfma(v2f a, v2f b, v2f c) {
#if __has_builtin(__builtin_elementwise_fma)
  return __builtin_elementwise_fma(a, b, c);
#else
  v2f r; r.x = fmaf(a.x, b.x, c.x); r.y = fmaf(a.y, b.y, c.y); return r;
#endif
}

// v_dot2_f32_f16: w.x*d.lo + w.y*d.hi + acc (f32 accumulate, full rate)
#if __has_builtin(__builtin_amdgcn_fdot2)
__device__ __forceinline__ float dot2h(v2h w, unsigned d, float acc) {
  return __builtin_amdgcn_fdot2(w, __builtin_bit_cast(v2h, d), acc, false);
}
#else
__device__ __forceinline__ float dot2h(v2h w, unsigned d, float acc) {
  const float fl = h2f((unsigned short)(d & 0xffffu));
  const float fh = h2f((unsigned short)(d >> 16));
  return fmaf((float)w.x, fl, fmaf((float)w.y, fh, acc));
}
#endif

#if __has_builtin(__builtin_amdgcn_permlane32_swap)
#define HAVE_PLS 1
__device__ __forceinline__ u2 pls(float x) {
  unsigned u = __float_as_uint(x);
  return __builtin_amdgcn_permlane32_swap(u, u, false, false);
}
#else
#define HAVE_PLS 0
#endif

// ---------------- K0: weight repack (one-time, trivial) --------------------
__global__ __launch_bounds__(64) void wpack(
    const float* __restrict__ Wih, const float* __restrict__ bih,
    const float* __restrict__ bhh, float* __restrict__ wp)
{
  const int t = threadIdx.x + blockIdx.x * 64;
  if (t < NG * 20) {
    const int g = t / 20, k = t - g * 20;
    const float L2E = 1.4426950408889634f;
    const float s = (g < 2 * HH) ? -L2E : 2.0f * L2E;
    wp[t] = (k < HH) ? Wih[g * HH + k] * s
                     : (bih[g] + (g < 2 * HH ? bhh[g] : 0.0f)) * s;
  }
}

// ---------------- K1: x-projection, pk_fma gate loop (proven ~80us) --------
__global__ __launch_bounds__(256) void xg_proj5(
    const float* __restrict__ x, const float* __restrict__ wp,
    unsigned short* __restrict__ xg)
{
  __shared__ __align__(16) float ls[256 * 33];
  const int tid = threadIdx.x;
  const size_t pair0 = (size_t)blockIdx.x * 256;

  {
    const float* __restrict__ src = x + pair0 * HH;
#pragma unroll
    for (int j = 0; j < HH; ++j) ls[j * 256 + tid] = src[j * 256 + tid];
  }
  __syncthreads();

  v2f xv2[10];
#pragma unroll
  for (int j = 0; j < 9; ++j)
    xv2[j] = mk2(ls[tid * HH + 2 * j], ls[tid * HH + 2 * j + 1]);
  xv2[9] = mk2(ls[tid * HH + 18], 0.0f);
  __syncthreads();

  unsigned short* __restrict__ lsh = (unsigned short*)ls;  // [256][66]
#pragma unroll 1
  for (int g = 0; g < NG; ++g) {
    const v2f* __restrict__ wr = (const v2f*)(wp + g * 20);  // 8B-aligned
    v2f a0 = mk2(wp[g * 20 + HH], 0.0f), a1 = mk2(0.0f, 0.0f);
#pragma unroll
    for (int j = 0; j < 5; ++j)  a0 = vfma(xv2[j], wr[j], a0);
#pragma unroll
    for (int j = 5; j < 10; ++j) a1 = vfma(xv2[j], wr[j], a1);
    const v2f sv = a0 + a1;
    lsh[tid * 66 + g] = f2h(sv.x + sv.y);
  }
#pragma unroll
  for (int g = NG; g < SL; ++g) lsh[tid * 66 + g] = 0;
  __syncthreads();

  const unsigned* __restrict__ lsd = (const unsigned*)ls;
  unsigned* __restrict__ xgd = (unsigned*)xg;
#pragma unroll
  for (int i = 0; i < 32; ++i) {
    const int D = tid + i * 256;
    xgd[pair0 * 32 + D] = lsd[(D >> 5) * 33 + (D & 31)];
  }
}

// ---------------- K2: recurrence (rec8 + xv folded into dot init) ----------
// 57-spread; lane 57 = oproj rider. For sigmoid-only lanes (r, z) the staged
// xv is folded into the dot init, deleting the `pre = xv + preh` add from the
// r-lane critical path (sig fires straight off the dot). n-lanes and lane 57
// keep xv separate (n needs it inside r*(...)+xv; 57's preh must stay = out).
__global__ void __launch_bounds__(64)
__attribute__((amdgpu_waves_per_eu(1, 1)))
gru_rec9(const unsigned short* __restrict__ xg, const float* __restrict__ Whh,
         const float* __restrict__ bhh, const float* __restrict__ Wout,
         const float* __restrict__ bout, float* __restrict__ out)
{
  __shared__ __align__(16) unsigned short hsh16[64];
  const int b = blockIdx.x;
  const int lane = threadIdx.x;
  const float L2E = 1.4426950408889634f;

  int row;
  if (lane < 32)      row = lane;          // r 0-18 (h owners), z 19-31
  else if (lane < 51) row = lane + 6;      // n 38-56
  else if (lane < 57) row = lane - 19;     // z 32-37
  else                row = 37;            // dup (lane 57 overridden below)
  const bool isn = (row >= 2 * HH);
  const bool isO = (lane == 57);           // oproj rider lane
  const bool fold = !(isn || isO);         // r/z lanes: fold xv into dot init
  const float s = isn ? (2.0f * L2E) : -L2E;

  v2h wh16[10];
#pragma unroll
  for (int j = 0; j < 10; ++j) {
    const int k0 = 2 * j, k1 = 2 * j + 1;
    const float w0 = isO ? Wout[k0] : s * Whh[row * HH + k0];
    const float w1 = (k1 < HH) ? (isO ? Wout[k1] : s * Whh[row * HH + k1]) : 0.0f;
    wh16[j].x = (_Float16)w0;
    wh16[j].y = (_Float16)w1;
  }
  const float dinit = isO ? bout[0] : (isn ? (2.0f * L2E * bhh[row]) : 0.0f);

  const int il = lane < HH ? lane : HH - 1;
  const int zaddr = ((il < 13) ? (19 + il) : (38 + il)) * 4;

#if HAVE_PLS
  bool loIsX;
  {
    unsigned l = (unsigned)lane;
    u2 pr = __builtin_amdgcn_permlane32_swap(l, l, false, false);
    loIsX = ((unsigned)__builtin_amdgcn_readlane((int)pr.x, 32) < 32u);
  }
#define LOBCAST(val, dst) do { u2 _s = pls(val);                        \
    dst = __uint_as_float(loIsX ? _s.x : _s.y); } while (0)
#define HIBCAST(val, dst) do { u2 _s = pls(val);                        \
    dst = __uint_as_float(loIsX ? _s.y : _s.x); } while (0)
#else
  const int loaddr = (lane & 31) * 4;
  const int hiaddr = ((lane & 31) | 32) * 4;
#define LOBCAST(val, dst) dst = __uint_as_float((unsigned)              \
    __builtin_amdgcn_ds_bpermute(loaddr, (int)__float_as_uint(val)))
#define HIBCAST(val, dst) dst = __uint_as_float((unsigned)              \
    __builtin_amdgcn_ds_bpermute(hiaddr, (int)__float_as_uint(val)))
#endif

  float h = 0.0f;     // lane i<19 owns h_i (f32); broadcast copy is f16

  const unsigned short* __restrict__ xb = xg + (size_t)b * SL + row;
#define LOADX(dst, trow) do { dst = xb[(size_t)(trow) * (NB * SL)]; } while (0)

  unsigned short s0, s1, s2, s3, s4, s5, s6, s7;
  LOADX(s0, 0); LOADX(s1, 1); LOADX(s2, 2); LOADX(s3, 3);
  LOADX(s4, 4); LOADX(s5, 5); LOADX(s6, 6); LOADX(s7, 7);

  // double-buffered packed h_{t-1}: P=h0..7, R=h8..15, Q=h16..18+pad
  u32x4 Pa = {0,0,0,0}, Ra = {0,0,0,0}, Pb, Rb;
  u32x2 Qa = {0,0}, Qb;

#define HDOT(init, Pi, Ri, Qi, dstvar) do {                             \
    float _a0 = (init), _a1 = 0.0f;                                     \
    _a0 = dot2h(wh16[0], Pi.x, _a0); _a1 = dot2h(wh16[1], Pi.y, _a1);   \
    _a0 = dot2h(wh16[2], Pi.z, _a0); _a1 = dot2h(wh16[3], Pi.w, _a1);   \
    _a0 = dot2h(wh16[4], Ri.x, _a0); _a1 = dot2h(wh16[5], Ri.y, _a1);   \
    _a0 = dot2h(wh16[6], Ri.z, _a0); _a1 = dot2h(wh16[7], Ri.w, _a1);   \
    _a0 = dot2h(wh16[8], Qi.x, _a0); _a1 = dot2h(wh16[9], Qi.y, _a1);   \
    dstvar = _a0 + _a1;                                                 \
  } while (0)

#define BODY(tcur, slot, Pi, Ri, Qi, Po, Ro, Qo, ovar) do {             \
    /* xv + fold-init are off-chain (slot data is 8 steps old) */       \
    const float xv = h2f(slot);                                         \
    const float init = fold ? (dinit + xv) : dinit;                     \
    float preh; HDOT(init, Pi, Ri, Qi, preh);                           \
    ovar = preh;                 /* lane 57: = out[t-1] (bo included) */ \
    /* r/z lanes: sig directly off the dot (xv already folded) */       \
    const float sig = frcp(fexp2(preh) + 1.0f);                         \
    const int zzi = __builtin_amdgcn_ds_bpermute(                       \
        zaddr, (int)__float_as_uint(sig));                              \
    float rr; LOBCAST(sig, rr);                                         \
    const float arg = fmaf(rr, preh, xv);  /* n lanes: xv separate */   \
    const float nn = fmaf(-2.0f, frcp(fexp2(arg) + 1.0f), 1.0f);        \
    float nh; HIBCAST(nn, nh);                                          \
    const float zz = __uint_as_float((unsigned)zzi);                    \
    const float hm = h - nh;               /* off-tail (nh early) */    \
    h = fmaf(zz, hm, nh);                  /* one op after zz tail */   \
    hsh16[lane] = f2h(h);                                               \
    Po = *(const u32x4*)&hsh16[0];                                      \
    Ro = *(const u32x4*)&hsh16[8];                                      \
    Qo = *(const u32x2*)&hsh16[16];                                     \
    { const int _tl = ((tcur) + 8 < TT) ? (tcur) + 8 : TT - 1;          \
      LOADX(slot, _tl); }                                               \
  } while (0)

  float o0, o1, o2, o3, o4, o5, o6, o7;
  float* __restrict__ ob = out + b;

  for (int t = 0; t < TT; t += 8) {
    BODY(t + 0, s0, Pa, Ra, Qa, Pb, Rb, Qb, o0);
    BODY(t + 1, s1, Pb, Rb, Qb, Pa, Ra, Qa, o1);
    BODY(t + 2, s2, Pa, Ra, Qa, Pb, Rb, Qb, o2);
    BODY(t + 3, s3, Pb, Rb, Qb, Pa, Ra, Qa, o3);
    BODY(t + 4, s4, Pa, Ra, Qa, Pb, Rb, Qb, o4);
    BODY(t + 5, s5, Pb, Rb, Qb, Pa, Ra, Qa, o5);
    BODY(t + 6, s6, Pa, Ra, Qa, Pb, Rb, Qb, o6);
    BODY(t + 7, s7, Pb, Rb, Qb, Pa, Ra, Qa, o7);
    if (lane == 57) {
      ob[(size_t)((t > 0) ? t - 1 : 0) * NB] = o0;  // junk@t=0, overwritten
      ob[(size_t)(t + 0) * NB] = o1;
      ob[(size_t)(t + 1) * NB] = o2;
      ob[(size_t)(t + 2) * NB] = o3;
      ob[(size_t)(t + 3) * NB] = o4;
      ob[(size_t)(t + 4) * NB] = o5;
      ob[(size_t)(t + 5) * NB] = o6;
      ob[(size_t)(t + 6) * NB] = o7;
    }
  }

  // epilogue: out[TT-1] from the final broadcast (state ended in Pa/Ra/Qa)
  {
    float oe; HDOT(dinit, Pa, Ra, Qa, oe);
    if (lane == 57) ob[(size_t)(TT - 1) * NB] = oe;
  }

#undef LOADX
#undef BODY
#undef HDOT
#undef LOBCAST
#undef HIBCAST
}

// ---------------- Fallback: round-8 fused kernel (proven, 555us) ----------
__global__ void __launch_bounds__(64)
__attribute__((amdgpu_waves_per_eu(1, 1)))
gru57_v4(const float* __restrict__ x, const float* __restrict__ Wih,
         const float* __restrict__ Whh, const float* __restrict__ bih,
         const float* __restrict__ bhh, const float* __restrict__ Wout,
         const float* __restrict__ bout, float* __restrict__ out)
{
  const int b = blockIdx.x;
  const int lane = threadIdx.x;
  const float L2E = 1.4426950408889634f;

  int row;
  if (lane < 32)      row = lane;
  else if (lane < 51) row = lane + 6;
  else if (lane < 57) row = lane - 19;
  else                row = 37;
  const bool isn = (row >= 2 * HH);
  const float scale = isn ? (2.0f * L2E) : L2E;

  v2f wx2[10], wh2[10], wo2[10];
#pragma unroll
  for (int j = 0; j < 10; ++j) {
    const int k0 = 2 * j, k1 = 2 * j + 1;
    wx2[j].x = Wih[row * HH + k0] * scale;
    wx2[j].y = (k1 < HH) ? Wih[row * HH + k1] * scale : 0.0f;
    wh2[j].x = Whh[row * HH + k0] * scale;
    wh2[j].y = (k1 < HH) ? Whh[row * HH + k1] * scale : 0.0f;
    wo2[j].x = Wout[k0];
    wo2[j].y = (k1 < HH) ? Wout[k1] : 0.0f;
  }
  const float bxv = bih[row] * scale, bhv = bhh[row] * scale;
  const float ax0 = isn ? bxv : (bxv + bhv);
  const float ah0 = isn ? bhv : 0.0f;
  const float bo  = bout[0];

  const int il = lane < HH ? lane : HH - 1;
  const int zaddr = ((il < 13) ? (19 + il) : (38 + il)) * 4;

#if HAVE_PLS
  bool loIsX;
  {
    unsigned l = (unsigned)lane;
    u2 pr = __builtin_amdgcn_permlane32_swap(l, l, false, false);
    loIsX = ((unsigned)__builtin_amdgcn_readlane((int)pr.x, 32) < 32u);
  }
#define LOBCAST(val, dst) do { u2 _s = pls(val);                        \
    dst = __uint_as_float(loIsX ? _s.x : _s.y); } while (0)
#define HIBCAST(val, dst) do { u2 _s = pls(val);                        \
    dst = __uint_as_float(loIsX ? _s.y : _s.x); } while (0)
#else
  const int loaddr = (lane & 31) * 4;
  const int hiaddr = ((lane & 31) | 32) * 4;
#define LOBCAST(val, dst) dst = __uint_as_float((unsigned)              \
    __builtin_amdgcn_ds_bpermute(loaddr, (int)__float_as_uint(val)))
#define HIBCAST(val, dst) dst = __uint_as_float((unsigned)              \
    __builtin_amdgcn_ds_bpermute(hiaddr, (int)__float_as_uint(val)))
#endif

  float h = 0.0f;
  v2f sh2[10];
#pragma unroll
  for (int j = 0; j < 10; ++j) sh2[j] = mk2(0.f, 0.f);

  const int kx = lane < HH ? lane : HH - 1;
  const float* __restrict__ xbase = x + (size_t)b * HH + kx;

#define LOADXF(dst, trow) do { dst = xbase[(size_t)(trow) * (NB * HH)]; } while (0)
#define XBCAST(slot, xu) do {                                           \
    _Pragma("unroll")                                                   \
    for (int _j = 0; _j < 9; ++_j) {                                    \
      xu[_j].x = rlf(slot, 2 * _j);                                     \
      xu[_j].y = rlf(slot, 2 * _j + 1);                                 \
    }                                                                   \
    xu[9].x = rlf(slot, 18); xu[9].y = 0.0f;                            \
  } while (0)
#define XDOT(xu, dstvar) do {                                           \
    v2f _aA = mk2(ax0, 0.0f), _aB = mk2(0.0f, 0.0f);                    \
    _Pragma("unroll")                                                   \
    for (int _j = 0; _j < 5; ++_j)  _aA = vfma(xu[_j], wx2[_j], _aA);   \
    _Pragma("unroll")                                                   \
    for (int _j = 5; _j < 10; ++_j) _aB = vfma(xu[_j], wx2[_j], _aB);   \
    const v2f _s = _aA + _aB;                                           \
    dstvar = _s.x + _s.y;                                               \
  } while (0)

  float xlA, xlB, xlC, xlD;
  LOADXF(xlA, 0); LOADXF(xlB, 1); LOADXF(xlC, 2); LOADXF(xlD, 3);
  float prex;
  { v2f xu0[10]; XBCAST(xlA, xu0); XDOT(xu0, prex); }

#define BODYF(tcur, nslot, lslot) do {                                  \
    v2f ahA = mk2(ah0, 0.0f), ahB = mk2(0.0f, 0.0f);                    \
    _Pragma("unroll")                                                   \
    for (int _j = 0; _j < 5; ++_j)  ahA = vfma(sh2[_j], wh2[_j], ahA);  \
    _Pragma("unroll")                                                   \
    for (int _j = 5; _j < 10; ++_j) ahB = vfma(sh2[_j], wh2[_j], ahB);  \
    float prexN;                                                        \
    { v2f _xu[10]; XBCAST(nslot, _xu); XDOT(_xu, prexN); }              \
    { const int _tl = ((tcur) + 4 < TT) ? (tcur) + 4 : TT - 1;          \
      LOADXF(lslot, _tl); }                                             \
    const v2f ahv = ahA + ahB;                                          \
    const float preh = ahv.x + ahv.y;                                   \
    const float pre  = prex + preh;                                     \
    const float sig  = frcp(1.0f + fexp2(-pre));                        \
    const int zzi = __builtin_amdgcn_ds_bpermute(                       \
        zaddr, (int)__float_as_uint(sig));                              \
    float rr; LOBCAST(sig, rr);                                         \
    const float npre = fmaf(rr, preh, prex);                            \
    const float nn = fmaf(-2.0f, frcp(fexp2(npre) + 1.0f), 1.0f);       \
    float nh; HIBCAST(nn, nh);                                          \
    const float zz = __uint_as_float((unsigned)zzi);                    \
    h = fmaf(zz, h - nh, nh);                                           \
    _Pragma("unroll")                                                   \
    for (int _j = 0; _j < 9; ++_j) {                                    \
      sh2[_j].x = rlf(h, 2 * _j);                                       \
      sh2[_j].y = rlf(h, 2 * _j + 1);                                   \
    }                                                                   \
    sh2[9].x = rlf(h, 18); sh2[9].y = 0.0f;                             \
    v2f oA = mk2(bo, 0.0f), oB = mk2(0.0f, 0.0f);                       \
    _Pragma("unroll")                                                   \
    for (int _j = 0; _j < 5; ++_j)  oA = vfma(sh2[_j], wo2[_j], oA);    \
    _Pragma("unroll")                                                   \
    for (int _j = 5; _j < 10; ++_j) oB = vfma(sh2[_j], wo2[_j], oB);    \
    const v2f ov = oA + oB;                                             \
    if (lane == 0) out[(size_t)(tcur) * NB + b] = ov.x + ov.y;          \
    prex = prexN;                                                       \
  } while (0)

  for (int t = 0; t < TT; t += 4) {
    BODYF(t + 0, xlB, xlA);
    BODYF(t + 1, xlC, xlB);
    BODYF(t + 2, xlD, xlC);
    BODYF(t + 3, xlA, xlD);
  }

#undef LOADXF
#undef XBCAST
#undef XDOT
#undef BODYF
#undef LOBCAST
#undef HIBCAST
}

extern "C" void kernel_launch(void* const* d_in, const int* in_sizes, int n_in,
                              void* d_out, int out_size, void* d_ws, size_t ws_size,
                              hipStream_t stream) {
  const float* x    = (const float*)d_in[0];
  const float* Wih  = (const float*)d_in[1];
  const float* Whh  = (const float*)d_in[2];
  const float* bih  = (const float*)d_in[3];
  const float* bhh  = (const float*)d_in[4];
  const float* Wout = (const float*)d_in[5];
  const float* bout = (const float*)d_in[6];
  float* out = (float*)d_out;

  const size_t xg_bytes = (size_t)TT * NB * SL * sizeof(unsigned short); // 256MB
  const size_t wp_bytes = (size_t)NG * 20 * sizeof(float);               // 4.6KB
  if (ws_size >= xg_bytes + wp_bytes) {
    unsigned short* xgws = (unsigned short*)d_ws;
    float* wpws = (float*)((char*)d_ws + xg_bytes);
    wpack<<<dim3((NG * 20 + 63) / 64), dim3(64), 0, stream>>>(
        Wih, bih, bhh, wpws);
    xg_proj5<<<dim3((TT * NB) / 256), dim3(256), 0, stream>>>(
        x, wpws, xgws);
    gru_rec9<<<dim3(NB), dim3(64), 0, stream>>>(
        xgws, Whh, bhh, Wout, bout, out);
  } else {
    gru57_v4<<<dim3(NB), dim3(64), 0, stream>>>(
        x, Wih, Whh, bih, bhh, Wout, bout, out);
  }
}